// Round 14
// baseline (235.096 us; speedup 1.0000x reference)
//
#include <hip/hip_runtime.h>
#include <hip/hip_fp16.h>
#include <stdint.h>
#include <stddef.h>

#define FEAT 128
#define BKT_SHIFT 8           // 256 nodes per bucket
#define TILE 4096             // edges per block in bucket passes
#define MAXB 400              // max buckets supported (n <= 102400)
#define CAP 4608              // fixed region size per bucket (mean 4096 + 8 sigma)

typedef _Float16 half8 __attribute__((ext_vector_type(8)));
typedef float f32x4 __attribute__((ext_vector_type(4)));

// ---------------- init: zero bucket cursors / allocCtr + W fp16-transpose (128 blocks) ----------------

__global__ __launch_bounds__(256) void k_initB(int* __restrict__ cursorPad, int* __restrict__ allocCtr,
                                               const float* __restrict__ W1, const float* __restrict__ W2,
                                               _Float16* __restrict__ Wt1, _Float16* __restrict__ Wt2) {
  int i = blockIdx.x * 256 + threadIdx.x;   // 0..32767
  if (i < MAXB * 16) cursorPad[i] = 0;
  if (i == 0) allocCtr[0] = 0;
  int which = i >> 14, rem = i & 16383;
  int k = rem >> 7, nn = rem & 127;
  (which ? Wt2 : Wt1)[nn * 128 + k] = (_Float16)((which ? W2 : W1)[rem]);
}

// ---------------- fused: edge bucket-scatter (blocks < tb)  ||  GEMM-1 U1 = x@W1 (blocks >= tb) ----------------
// bscatter: per-block LDS hist -> one reservation per bucket -> LDS-rank scatter.
// pairs entry: (src << 8) | (dst & 255).
// gemm: unscaled (dis not ready yet); U1 fp16. A-frag from fp32 x converted in-register.

__global__ __launch_bounds__(256, 2) void k_build(const int* __restrict__ src, const int* __restrict__ dst,
                                                  int* __restrict__ cursorPad, int* __restrict__ pairs,
                                                  int E, int B, int tb,
                                                  const float* __restrict__ x, const _Float16* __restrict__ Wt1,
                                                  __half* __restrict__ U1, int n, int nwaves) {
  __shared__ int h[MAXB];
  __shared__ int cur[MAXB];
  if (blockIdx.x < tb) {
    // ---- bscatter ----
    int t0 = blockIdx.x * TILE;
    int end = min(E, t0 + TILE);
    for (int i = threadIdx.x; i < B; i += 256) h[i] = 0;
    __syncthreads();
    if (end - t0 == TILE) {
      int d[16];
#pragma unroll
      for (int k = 0; k < 16; ++k) {
        d[k] = dst[t0 + threadIdx.x + k * 256];
        atomicAdd(&h[d[k] >> BKT_SHIFT], 1);
      }
      __syncthreads();
      for (int i = threadIdx.x; i < B; i += 256)
        cur[i] = h[i] ? atomicAdd(&cursorPad[i * 16], h[i]) : 0;
      __syncthreads();
#pragma unroll
      for (int k = 0; k < 16; ++k) {
        int e = t0 + threadIdx.x + k * 256;
        int b = d[k] >> BKT_SHIFT;
        int pos = atomicAdd(&cur[b], 1);
        if (pos < CAP) pairs[b * CAP + pos] = (src[e] << 8) | (d[k] & 255);
      }
    } else {
      for (int e = t0 + threadIdx.x; e < end; e += 256) atomicAdd(&h[dst[e] >> BKT_SHIFT], 1);
      __syncthreads();
      for (int i = threadIdx.x; i < B; i += 256)
        cur[i] = h[i] ? atomicAdd(&cursorPad[i * 16], h[i]) : 0;
      __syncthreads();
      for (int e = t0 + threadIdx.x; e < end; e += 256) {
        int dd = dst[e];
        int b = dd >> BKT_SHIFT;
        int pos = atomicAdd(&cur[b], 1);
        if (pos < CAP) pairs[b * CAP + pos] = (src[e] << 8) | (dd & 255);
      }
    }
  } else {
    // ---- gemm-1: U1 = x @ W1 (fp16, unscaled) ----
    const int wid = ((blockIdx.x - tb) * 256 + threadIdx.x) >> 6;
    const int lane = threadIdx.x & 63;
    const int lrow = lane & 15;
    const int lk8 = (lane >> 4) * 8;
    const int ngroups = (n + 15) >> 4;

    half8 bf[8][4];
#pragma unroll
    for (int c = 0; c < 8; ++c)
#pragma unroll
      for (int kk = 0; kk < 4; ++kk)
        bf[c][kk] = *(const half8*)(Wt1 + (size_t)(c * 16 + lrow) * 128 + kk * 32 + lk8);

    for (int g = wid; g < ngroups; g += nwaves) {
      int ar = g * 16 + lrow; if (ar >= n) ar = n - 1;
      const float* arow = x + (size_t)ar * 128 + lk8;
      half8 af[4];
#pragma unroll
      for (int kk = 0; kk < 4; ++kk) {
        float4 v0 = *(const float4*)(arow + kk * 32);
        float4 v1 = *(const float4*)(arow + kk * 32 + 4);
        af[kk] = (half8){(_Float16)v0.x, (_Float16)v0.y, (_Float16)v0.z, (_Float16)v0.w,
                         (_Float16)v1.x, (_Float16)v1.y, (_Float16)v1.z, (_Float16)v1.w};
      }
      f32x4 acc[8];
#pragma unroll
      for (int c = 0; c < 8; ++c) acc[c] = (f32x4){0.f, 0.f, 0.f, 0.f};
#pragma unroll
      for (int kk = 0; kk < 4; ++kk)
#pragma unroll
        for (int c = 0; c < 8; ++c)
          acc[c] = __builtin_amdgcn_mfma_f32_16x16x32_f16(af[kk], bf[c][kk], acc[c], 0, 0, 0);
      const int r0 = g * 16 + (lane >> 4) * 4;
#pragma unroll
      for (int r = 0; r < 4; ++r) {
        int row = r0 + r;
        if (row < n)
#pragma unroll
          for (int c = 0; c < 8; ++c)
            U1[(size_t)row * 128 + c * 16 + lrow] = __float2half_rn(acc[c][r]);
      }
    }
  }
}

// ---------------- per-bucket CSR + T1 = dis .* U1 epilogue ----------------

__global__ __launch_bounds__(256) void k_csrT(const int* __restrict__ pairs, const int* __restrict__ cursorPad,
                                              int* __restrict__ cnt, int* __restrict__ rowstart,
                                              float* __restrict__ dis, int* __restrict__ allocCtr,
                                              int* __restrict__ adj,
                                              const __half* __restrict__ U1, __half* __restrict__ T1, int n) {
  __shared__ int deg[256];
  __shared__ int scan[256];
  __shared__ int curs[256];
  __shared__ float disS[256];
  __shared__ int base;
  int b = blockIdx.x, t = threadIdx.x;
  int nodeBase = b << BKT_SHIFT;
  int e0 = b * CAP;
  int ecnt = min(cursorPad[b * 16], CAP);
  deg[t] = 0;
  __syncthreads();
  for (int i = t; i < ecnt; i += 256) atomicAdd(&deg[pairs[e0 + i] & 255], 1);
  __syncthreads();
  int d = deg[t];
  int padded = (d + 3) & ~3;            // 16B-aligned adj rows for k_agg int4 loads
  scan[t] = padded;
  __syncthreads();
  for (int off = 1; off < 256; off <<= 1) {
    int xg = scan[t];
    int y = (t >= off) ? scan[t - off] : 0;
    __syncthreads();
    scan[t] = xg + y;
    __syncthreads();
  }
  int excl = scan[t] - padded;
  if (t == 255) base = atomicAdd(allocCtr, scan[t]);   // one bump per block
  __syncthreads();
  int rs = base + excl;
  int node = nodeBase + t;
  float dv = rsqrtf((float)(d + 1));     // +1: self-loop included in reference degree
  disS[t] = dv;
  if (node < n) {
    rowstart[node] = rs;
    cnt[node] = d;
    dis[node] = dv;
  }
  curs[t] = rs;
  __syncthreads();                        // also publishes disS for the epilogue
  for (int i = t; i < ecnt; i += 256) {
    int pk = pairs[e0 + i];
    int pos = atomicAdd(&curs[pk & 255], 1);           // LDS cursor; writes hit block's own region
    adj[pos] = pk >> 8;
  }
  // epilogue: T1[node] = dis[node] * U1[node] for the block's 256 nodes (coalesced 64KB in/out)
  for (int idx = t; idx < 256 * 64; idx += 256) {
    int r = idx >> 6, c = idx & 63;
    int nd = nodeBase + r;
    if (nd >= n) continue;
    float di = disS[r];
    float2 v = __half22float2(((const __half2*)(U1 + (size_t)nd * FEAT))[c]);
    ((__half2*)(T1 + (size_t)nd * FEAT))[c] = __floats2half2_rn(di * v.x, di * v.y);
  }
}

// ---------------- MFMA GEMM (standalone, layer 2): T2 = dis .* (H1 @ W2), fp16 ----------------

__global__ __launch_bounds__(256, 2) void k_gemm2(const __half* __restrict__ Av,
                                                  const _Float16* __restrict__ Wt,
                                                  const float* __restrict__ dis,
                                                  __half* __restrict__ T, int n, int nwaves) {
  const int wid = (blockIdx.x * 256 + threadIdx.x) >> 6;
  const int lane = threadIdx.x & 63;
  const int lrow = lane & 15;
  const int lk8 = (lane >> 4) * 8;
  const int ngroups = (n + 15) >> 4;

  half8 bf[8][4];
#pragma unroll
  for (int c = 0; c < 8; ++c)
#pragma unroll
    for (int kk = 0; kk < 4; ++kk)
      bf[c][kk] = *(const half8*)(Wt + (size_t)(c * 16 + lrow) * 128 + kk * 32 + lk8);

  for (int g = wid; g < ngroups; g += nwaves) {
    int ar = g * 16 + lrow; if (ar >= n) ar = n - 1;
    const _Float16* arow = (const _Float16*)Av + (size_t)ar * 128 + lk8;
    half8 af[4];
#pragma unroll
    for (int kk = 0; kk < 4; ++kk) af[kk] = *(const half8*)(arow + kk * 32);
    f32x4 acc[8];
#pragma unroll
    for (int c = 0; c < 8; ++c) acc[c] = (f32x4){0.f, 0.f, 0.f, 0.f};
#pragma unroll
    for (int kk = 0; kk < 4; ++kk)
#pragma unroll
      for (int c = 0; c < 8; ++c)
        acc[c] = __builtin_amdgcn_mfma_f32_16x16x32_f16(af[kk], bf[c][kk], acc[c], 0, 0, 0);
    const int r0 = g * 16 + (lane >> 4) * 4;
#pragma unroll
    for (int r = 0; r < 4; ++r) {
      int row = r0 + r;
      if (row < n) {
        float sc = dis[row];
#pragma unroll
        for (int c = 0; c < 8; ++c)
          T[(size_t)row * 128 + c * 16 + lrow] = __float2half_rn(sc * acc[c][r]);
      }
    }
  }
}

// ---------------- aggregation + bias + relu: val[i] = relu(dis[i]*(t[i] + sum_j t[j]) + b) ----------------
// t pre-scaled by dis. FINAL: write fp32 out; else fp16 h (layer-2 GEMM input).

template <bool FINAL>
__global__ __launch_bounds__(256) void k_agg(const __half* __restrict__ t, const float* __restrict__ bias,
                                             const int* __restrict__ adj, const int* __restrict__ rowstart,
                                             const int* __restrict__ cnt, const float* __restrict__ dis,
                                             void* __restrict__ outV, int n) {
  int node = blockIdx.x * 4 + (threadIdx.x >> 6);
  if (node >= n) return;
  int lane = threadIdx.x & 63;
  int rs = rowstart[node];
  int d = cnt[node];
  float di = dis[node];
  float2 bb = ((const float2*)bias)[lane];
  float2 a = __half22float2(((const __half2*)(t + (size_t)node * FEAT))[lane]);
  float ax = a.x, ay = a.y;
  int p = rs, e = rs + d;
#pragma unroll 2
  for (; p + 4 <= e; p += 4) {
    int4 j4 = *(const int4*)(adj + p);   // aligned (rows 16B-aligned), wave-uniform
    float2 h0 = __half22float2(((const __half2*)(t + (size_t)j4.x * FEAT))[lane]);
    float2 h1 = __half22float2(((const __half2*)(t + (size_t)j4.y * FEAT))[lane]);
    float2 h2 = __half22float2(((const __half2*)(t + (size_t)j4.z * FEAT))[lane]);
    float2 h3 = __half22float2(((const __half2*)(t + (size_t)j4.w * FEAT))[lane]);
    ax += (h0.x + h1.x) + (h2.x + h3.x);
    ay += (h0.y + h1.y) + (h2.y + h3.y);
  }
  for (; p < e; ++p) {
    int j = adj[p];
    float2 hv = __half22float2(((const __half2*)(t + (size_t)j * FEAT))[lane]);
    ax += hv.x; ay += hv.y;
  }
  float vx = fmaxf(fmaf(di, ax, bb.x), 0.f);
  float vy = fmaxf(fmaf(di, ay, bb.y), 0.f);
  if (FINAL) ((float2*)((float*)outV + (size_t)node * FEAT))[lane] = make_float2(vx, vy);
  else       ((__half2*)((__half*)outV + (size_t)node * FEAT))[lane] = __floats2half2_rn(vx, vy);
}

// ---------------- launch ----------------

extern "C" void kernel_launch(void* const* d_in, const int* in_sizes, int n_in,
                              void* d_out, int out_size, void* d_ws, size_t ws_size,
                              hipStream_t stream) {
  const float* x  = (const float*)d_in[0];
  const int*   ei = (const int*)d_in[1];
  const float* W1 = (const float*)d_in[2];
  const float* b1 = (const float*)d_in[3];
  const float* W2 = (const float*)d_in[4];
  const float* b2 = (const float*)d_in[5];
  float* out = (float*)d_out;

  const int n = in_sizes[0] / FEAT;   // 100000
  const int E = in_sizes[1] / 2;      // 1600000
  const int B = (n + 255) >> BKT_SHIFT;   // 391 buckets (<= MAXB)
  const int* srcv = ei;
  const int* dstv = ei + E;

  uintptr_t p = (uintptr_t)d_ws;
  auto balloc = [&](size_t bytes) -> void* {
    void* r = (void*)p;
    p += (bytes + 255) & ~(size_t)255;
    return r;
  };
  __half*    U1   = (__half*)   balloc((size_t)n * FEAT * sizeof(__half)); // x@W1 (unscaled)
  __half*    T1   = (__half*)   balloc((size_t)n * FEAT * sizeof(__half)); // dis.*(x@W1)
  __half*    H1   = (__half*)   balloc((size_t)n * FEAT * sizeof(__half)); // h1 = relu(agg + b1)
  __half*    T2   = (__half*)   balloc((size_t)n * FEAT * sizeof(__half)); // dis.*(h1@W2)
  _Float16*  Wt1  = (_Float16*) balloc(128 * 128 * sizeof(_Float16));
  _Float16*  Wt2  = (_Float16*) balloc(128 * 128 * sizeof(_Float16));
  int*   cnt      = (int*)  balloc((size_t)n * sizeof(int));
  int*   rowstart = (int*)  balloc((size_t)n * sizeof(int));
  float* dis      = (float*)balloc((size_t)n * sizeof(float));
  int*   allocCtr = (int*)  balloc(256);
  int*   cursorPad= (int*)  balloc((size_t)MAXB * 16 * sizeof(int));       // 64B-padded bucket cursors
  int*   pairs    = (int*)  balloc((size_t)MAXB * CAP * sizeof(int));      // fixed bucket regions (packed)
  int*   adj      = (int*)  balloc(((size_t)E + 4 * (size_t)n) * sizeof(int)); // +pad for row alignment
  (void)ws_size; (void)n_in; (void)out_size;

  const int tb  = (E + TILE - 1) / TILE;          // 391 edge tiles
  const int ab  = (n + 3) / 4;                    // agg: 4 nodes (waves) per block
  const int gemmBlocks = 512;
  const int nwaves = gemmBlocks * 4;

  // init (zero cursors + W transposes), then build || gemm1 fused
  k_initB <<<128, 256, 0, stream>>>(cursorPad, allocCtr, W1, W2, Wt1, Wt2);
  k_build <<<tb + gemmBlocks, 256, 0, stream>>>(srcv, dstv, cursorPad, pairs, E, B, tb,
                                                x, Wt1, U1, n, nwaves);
  k_csrT  <<<B, 256, 0, stream>>>(pairs, cursorPad, cnt, rowstart, dis, allocCtr, adj, U1, T1, n);

  // layer 1 aggregation -> H1; layer 2 GEMM -> T2; layer 2 aggregation -> out
  k_agg<false> <<<ab, 256, 0, stream>>>(T1, b1, adj, rowstart, cnt, dis, H1, n);
  k_gemm2      <<<gemmBlocks, 256, 0, stream>>>(H1, Wt2, dis, T2, n, nwaves);
  k_agg<true>  <<<ab, 256, 0, stream>>>(T2, b2, adj, rowstart, cnt, dis, out, n);
}

// Round 15
// 212.870 us; speedup vs baseline: 1.1044x; 1.1044x over previous
//
#include <hip/hip_runtime.h>
#include <hip/hip_fp16.h>
#include <stdint.h>
#include <stddef.h>

#define FEAT 128
#define BKT_SHIFT 8           // 256 nodes per bucket
#define TILE 4096             // edges per block in bucket passes
#define MAXB 400              // max buckets supported (n <= 102400)
#define CAP 4608              // fixed region size per bucket (mean 4096 + 8 sigma)
#define PADMAX (CAP + 768)    // max padded adj span per bucket (ecnt + 3*256)

typedef _Float16 half8 __attribute__((ext_vector_type(8)));
typedef float f32x4 __attribute__((ext_vector_type(4)));

// ---------------- init: zero bucket cursors / allocCtr + W fp16-transpose (128 blocks) ----------------

__global__ __launch_bounds__(256) void k_initB(int* __restrict__ cursorPad, int* __restrict__ allocCtr,
                                               const float* __restrict__ W1, const float* __restrict__ W2,
                                               _Float16* __restrict__ Wt1, _Float16* __restrict__ Wt2) {
  int i = blockIdx.x * 256 + threadIdx.x;   // 0..32767
  if (i < MAXB * 16) cursorPad[i] = 0;
  if (i == 0) allocCtr[0] = 0;
  int which = i >> 14, rem = i & 16383;
  int k = rem >> 7, nn = rem & 127;
  (which ? Wt2 : Wt1)[nn * 128 + k] = (_Float16)((which ? W2 : W1)[rem]);
}

// ---------------- pass 1: bucket-scatter with LDS destination-ordered staging ----------------
// pairs entry: (src << 8) | (dst & 255). Write-out is bucket-sorted -> mostly-coalesced.

__global__ __launch_bounds__(256) void k_bscatter(const int* __restrict__ src, const int* __restrict__ dst,
                                                  int* __restrict__ cursorPad, int* __restrict__ pairs,
                                                  int E, int B) {
  __shared__ int h[MAXB];
  __shared__ int lbase[MAXB];
  __shared__ int cur[MAXB];
  __shared__ int hcnt[MAXB];
  __shared__ int staged[TILE];
  __shared__ int dests[TILE];
  const int tid = threadIdx.x;
  int t0 = blockIdx.x * TILE;
  int cnt = min(E - t0, TILE);

  for (int i = tid; i < B; i += 256) h[i] = 0;
  __syncthreads();

  if (cnt == TILE) {
    int d[16], s_[16];
#pragma unroll
    for (int k = 0; k < 16; ++k) {
      d[k] = dst[t0 + tid + k * 256];
      s_[k] = src[t0 + tid + k * 256];
      atomicAdd(&h[d[k] >> BKT_SHIFT], 1);
    }
    __syncthreads();
    // wave-0: exclusive scan of h[0..B) -> lbase (7 bins per lane)
    if (tid < 64) {
      int l = tid, b7 = l * 7;
      int v[7]; int sum = 0;
#pragma unroll
      for (int q = 0; q < 7; ++q) { int b = b7 + q; v[q] = (b < B) ? h[b] : 0; sum += v[q]; }
      int incl = sum;
      for (int off = 1; off < 64; off <<= 1) { int y = __shfl_up(incl, off); if (l >= off) incl += y; }
      int run = incl - sum;
#pragma unroll
      for (int q = 0; q < 7; ++q) { int b = b7 + q; if (b < B) lbase[b] = run; run += v[q]; }
    }
    for (int i = tid; i < B; i += 256) {
      cur[i] = h[i] ? atomicAdd(&cursorPad[i * 16], h[i]) : 0;   // in-bucket reservation
      hcnt[i] = 0;
    }
    __syncthreads();
#pragma unroll
    for (int k = 0; k < 16; ++k) {
      int b = d[k] >> BKT_SHIFT;
      int r = atomicAdd(&hcnt[b], 1);
      int li = lbase[b] + r;
      int pos = cur[b] + r;
      staged[li] = (s_[k] << 8) | (d[k] & 255);
      dests[li] = (pos < CAP) ? (b * CAP + pos) : -1;
    }
    __syncthreads();
    for (int i = tid; i < TILE; i += 256) {
      int dd = dests[i];
      if (dd >= 0) pairs[dd] = staged[i];     // destination-sorted -> coalesced runs
    }
  } else {
    // tail block (one): simple path
    for (int e = tid; e < cnt; e += 256) atomicAdd(&h[dst[t0 + e] >> BKT_SHIFT], 1);
    __syncthreads();
    for (int i = tid; i < B; i += 256) {
      cur[i] = h[i] ? atomicAdd(&cursorPad[i * 16], h[i]) : 0;
      hcnt[i] = 0;
    }
    __syncthreads();
    for (int e = tid; e < cnt; e += 256) {
      int dd = dst[t0 + e];
      int b = dd >> BKT_SHIFT;
      int pos = cur[b] + atomicAdd(&hcnt[b], 1);
      if (pos < CAP) pairs[b * CAP + pos] = (src[t0 + e] << 8) | (dd & 255);
    }
  }
}

// ---------------- pass 2: per-bucket CSR, fully LDS-staged (coalesced pairs read + adj write) ----------------

__global__ __launch_bounds__(256) void k_csr(const int* __restrict__ pairs, const int* __restrict__ cursorPad,
                                             int* __restrict__ cnt, int* __restrict__ rowstart,
                                             float* __restrict__ dis, int* __restrict__ allocCtr,
                                             int* __restrict__ adj, int n) {
  __shared__ int pr[CAP];
  __shared__ int stagedAdj[PADMAX];
  __shared__ int deg[256];
  __shared__ int lcur[256];
  __shared__ int wsum[4];
  __shared__ int sbase;
  const int b = blockIdx.x, t = threadIdx.x;
  const int w = t >> 6, lane = t & 63;
  const int nodeBase = b << BKT_SHIFT;
  const int e0 = b * CAP;
  const int ecnt = min(cursorPad[b * 16], CAP);

  deg[t] = 0;
  for (int i = t; i < ecnt; i += 256) pr[i] = pairs[e0 + i];   // coalesced, read once
  __syncthreads();
  for (int i = t; i < ecnt; i += 256) atomicAdd(&deg[pr[i] & 255], 1);
  __syncthreads();

  int d = deg[t];
  int padded = (d + 3) & ~3;            // 16B-aligned adj rows for k_agg int4 loads
  // exclusive scan of padded over 256 threads: wave shfl-scan + wave offsets
  int incl = padded;
  for (int off = 1; off < 64; off <<= 1) { int y = __shfl_up(incl, off); if (lane >= off) incl += y; }
  if (lane == 63) wsum[w] = incl;
  __syncthreads();
  int tot  = wsum[0] + wsum[1] + wsum[2] + wsum[3];
  int woff = (w > 0 ? wsum[0] : 0) + (w > 1 ? wsum[1] : 0) + (w > 2 ? wsum[2] : 0);
  int excl = woff + incl - padded;
  if (t == 0) sbase = atomicAdd(allocCtr, tot);   // one bump per block
  lcur[t] = excl;
  __syncthreads();

  int base = sbase;
  int node = nodeBase + t;
  if (node < n) {
    rowstart[node] = base + excl;
    cnt[node] = d;
    dis[node] = rsqrtf((float)(d + 1));  // +1: self-loop included in reference degree
  }
  for (int i = t; i < ecnt; i += 256) {
    int pk = pr[i];
    int li = atomicAdd(&lcur[pk & 255], 1);
    stagedAdj[li] = pk >> 8;
  }
  __syncthreads();
  for (int i = t; i < tot; i += 256) adj[base + i] = stagedAdj[i];   // fully coalesced
}

// ---------------- MFMA GEMM: T = dis .* (A @ W), fp16 out (pre-scaled gather table) ----------------
// A32: A is fp32 (layer-1 input x, converted in-register); else fp16 (h1).

template <bool A32>
__global__ __launch_bounds__(256, 2) void k_gemm(const void* __restrict__ Av,
                                                 const _Float16* __restrict__ Wt,
                                                 const float* __restrict__ dis,
                                                 __half* __restrict__ T, int n, int nwaves) {
  const int wid = (blockIdx.x * 256 + threadIdx.x) >> 6;
  const int lane = threadIdx.x & 63;
  const int lrow = lane & 15;
  const int lk8 = (lane >> 4) * 8;
  const int ngroups = (n + 15) >> 4;

  half8 bf[8][4];
#pragma unroll
  for (int c = 0; c < 8; ++c)
#pragma unroll
    for (int kk = 0; kk < 4; ++kk)
      bf[c][kk] = *(const half8*)(Wt + (size_t)(c * 16 + lrow) * 128 + kk * 32 + lk8);

  for (int g = wid; g < ngroups; g += nwaves) {
    int ar = g * 16 + lrow; if (ar >= n) ar = n - 1;
    half8 af[4];
    if (A32) {
      const float* arow = (const float*)Av + (size_t)ar * 128 + lk8;
#pragma unroll
      for (int kk = 0; kk < 4; ++kk) {
        float4 v0 = *(const float4*)(arow + kk * 32);
        float4 v1 = *(const float4*)(arow + kk * 32 + 4);
        af[kk] = (half8){(_Float16)v0.x, (_Float16)v0.y, (_Float16)v0.z, (_Float16)v0.w,
                         (_Float16)v1.x, (_Float16)v1.y, (_Float16)v1.z, (_Float16)v1.w};
      }
    } else {
      const _Float16* arow = (const _Float16*)Av + (size_t)ar * 128 + lk8;
#pragma unroll
      for (int kk = 0; kk < 4; ++kk) af[kk] = *(const half8*)(arow + kk * 32);
    }
    f32x4 acc[8];
#pragma unroll
    for (int c = 0; c < 8; ++c) acc[c] = (f32x4){0.f, 0.f, 0.f, 0.f};
#pragma unroll
    for (int kk = 0; kk < 4; ++kk)
#pragma unroll
      for (int c = 0; c < 8; ++c)
        acc[c] = __builtin_amdgcn_mfma_f32_16x16x32_f16(af[kk], bf[c][kk], acc[c], 0, 0, 0);
    const int r0 = g * 16 + (lane >> 4) * 4;
#pragma unroll
    for (int r = 0; r < 4; ++r) {
      int row = r0 + r;
      if (row < n) {
        float sc = dis[row];
#pragma unroll
        for (int c = 0; c < 8; ++c)
          T[(size_t)row * 128 + c * 16 + lrow] = __float2half_rn(sc * acc[c][r]);
      }
    }
  }
}

// ---------------- aggregation + bias + relu: val[i] = relu(dis[i]*(t[i] + sum_j t[j]) + b) ----------------
// t pre-scaled by dis. FINAL: write fp32 out; else fp16 h (layer-2 GEMM input).

template <bool FINAL>
__global__ __launch_bounds__(256) void k_agg(const __half* __restrict__ t, const float* __restrict__ bias,
                                             const int* __restrict__ adj, const int* __restrict__ rowstart,
                                             const int* __restrict__ cnt, const float* __restrict__ dis,
                                             void* __restrict__ outV, int n) {
  int node = blockIdx.x * 4 + (threadIdx.x >> 6);
  if (node >= n) return;
  int lane = threadIdx.x & 63;
  int rs = rowstart[node];
  int d = cnt[node];
  float di = dis[node];
  float2 bb = ((const float2*)bias)[lane];
  float2 a = __half22float2(((const __half2*)(t + (size_t)node * FEAT))[lane]);
  float ax = a.x, ay = a.y;
  int p = rs, e = rs + d;
#pragma unroll 2
  for (; p + 4 <= e; p += 4) {
    int4 j4 = *(const int4*)(adj + p);   // aligned (rows 16B-aligned), wave-uniform
    float2 h0 = __half22float2(((const __half2*)(t + (size_t)j4.x * FEAT))[lane]);
    float2 h1 = __half22float2(((const __half2*)(t + (size_t)j4.y * FEAT))[lane]);
    float2 h2 = __half22float2(((const __half2*)(t + (size_t)j4.z * FEAT))[lane]);
    float2 h3 = __half22float2(((const __half2*)(t + (size_t)j4.w * FEAT))[lane]);
    ax += (h0.x + h1.x) + (h2.x + h3.x);
    ay += (h0.y + h1.y) + (h2.y + h3.y);
  }
  for (; p < e; ++p) {
    int j = adj[p];
    float2 hv = __half22float2(((const __half2*)(t + (size_t)j * FEAT))[lane]);
    ax += hv.x; ay += hv.y;
  }
  float vx = fmaxf(fmaf(di, ax, bb.x), 0.f);
  float vy = fmaxf(fmaf(di, ay, bb.y), 0.f);
  if (FINAL) ((float2*)((float*)outV + (size_t)node * FEAT))[lane] = make_float2(vx, vy);
  else       ((__half2*)((__half*)outV + (size_t)node * FEAT))[lane] = __floats2half2_rn(vx, vy);
}

// ---------------- launch ----------------

extern "C" void kernel_launch(void* const* d_in, const int* in_sizes, int n_in,
                              void* d_out, int out_size, void* d_ws, size_t ws_size,
                              hipStream_t stream) {
  const float* x  = (const float*)d_in[0];
  const int*   ei = (const int*)d_in[1];
  const float* W1 = (const float*)d_in[2];
  const float* b1 = (const float*)d_in[3];
  const float* W2 = (const float*)d_in[4];
  const float* b2 = (const float*)d_in[5];
  float* out = (float*)d_out;

  const int n = in_sizes[0] / FEAT;   // 100000
  const int E = in_sizes[1] / 2;      // 1600000
  const int B = (n + 255) >> BKT_SHIFT;   // 391 buckets (<= MAXB)
  const int* srcv = ei;
  const int* dstv = ei + E;

  uintptr_t p = (uintptr_t)d_ws;
  auto balloc = [&](size_t bytes) -> void* {
    void* r = (void*)p;
    p += (bytes + 255) & ~(size_t)255;
    return r;
  };
  __half*    T1   = (__half*)   balloc((size_t)n * FEAT * sizeof(__half)); // dis.*(x@W1)
  __half*    H1   = (__half*)   balloc((size_t)n * FEAT * sizeof(__half)); // h1 = relu(agg + b1)
  __half*    T2   = (__half*)   balloc((size_t)n * FEAT * sizeof(__half)); // dis.*(h1@W2)
  _Float16*  Wt1  = (_Float16*) balloc(128 * 128 * sizeof(_Float16));
  _Float16*  Wt2  = (_Float16*) balloc(128 * 128 * sizeof(_Float16));
  int*   cnt      = (int*)  balloc((size_t)n * sizeof(int));
  int*   rowstart = (int*)  balloc((size_t)n * sizeof(int));
  float* dis      = (float*)balloc((size_t)n * sizeof(float));
  int*   allocCtr = (int*)  balloc(256);
  int*   cursorPad= (int*)  balloc((size_t)MAXB * 16 * sizeof(int));       // 64B-padded bucket cursors
  int*   pairs    = (int*)  balloc((size_t)MAXB * CAP * sizeof(int));      // fixed bucket regions (packed)
  int*   adj      = (int*)  balloc(((size_t)E + 4 * (size_t)n) * sizeof(int)); // +pad for row alignment
  (void)ws_size; (void)n_in; (void)out_size;

  const int tb  = (E + TILE - 1) / TILE;          // 391 edge tiles
  const int ab  = (n + 3) / 4;                    // agg: 4 nodes (waves) per block
  const int gemmBlocks = 512;
  const int nwaves = gemmBlocks * 4;

  // graph build (LDS-staged scatter + LDS-staged per-bucket CSR)
  k_initB   <<<128, 256, 0, stream>>>(cursorPad, allocCtr, W1, W2, Wt1, Wt2);
  k_bscatter<<<tb, 256, 0, stream>>>(srcv, dstv, cursorPad, pairs, E, B);
  k_csr     <<<B, 256, 0, stream>>>(pairs, cursorPad, cnt, rowstart, dis, allocCtr, adj, n);

  // layer 1: T1 = dis.*(x@W1)  ->  H1 = relu(di*agg(T1) + b1)
  k_gemm<true>  <<<gemmBlocks, 256, 0, stream>>>(x, Wt1, dis, T1, n, nwaves);
  k_agg<false>  <<<ab, 256, 0, stream>>>(T1, b1, adj, rowstart, cnt, dis, H1, n);

  // layer 2: T2 = dis.*(H1@W2) ->  out = relu(di*agg(T2) + b2)  (pooling is identity)
  k_gemm<false> <<<gemmBlocks, 256, 0, stream>>>(H1, Wt2, dis, T2, n, nwaves);
  k_agg<true>   <<<ab, 256, 0, stream>>>(T2, b2, adj, rowstart, cnt, dis, out, n);
}

// Round 16
// 212.230 us; speedup vs baseline: 1.1077x; 1.0030x over previous
//
#include <hip/hip_runtime.h>
#include <hip/hip_fp16.h>
#include <stdint.h>
#include <stddef.h>

#define FEAT 128
#define BKT_SHIFT 8           // 256 nodes per bucket
#define TILE 4096             // edges per block in bucket passes
#define MAXB 400              // max buckets supported (n <= 102400)
#define CAP 4608              // fixed region size per bucket (mean 4096 + 8 sigma)
#define PADMAX (CAP + 768)    // max padded adj span per bucket (ecnt + 3*256)

typedef _Float16 half8 __attribute__((ext_vector_type(8)));
typedef float f32x4 __attribute__((ext_vector_type(4)));

// ---------------- pass 1: bucket-scatter with LDS destination-ordered staging ----------------
// Blocks 0..127 additionally perform the W fp16-transpose (tiny, hidden under edge work).
// pairs entry: (src << 8) | (dst & 255). Write-out is bucket-sorted -> mostly-coalesced.

__global__ __launch_bounds__(256) void k_bscatter(const int* __restrict__ src, const int* __restrict__ dst,
                                                  int* __restrict__ cursorPad, int* __restrict__ pairs,
                                                  int E, int B,
                                                  const float* __restrict__ W1, const float* __restrict__ W2,
                                                  _Float16* __restrict__ Wt1, _Float16* __restrict__ Wt2) {
  __shared__ int h[MAXB];
  __shared__ int lbase[MAXB];
  __shared__ int cur[MAXB];
  __shared__ int hcnt[MAXB];
  __shared__ int staged[TILE];
  __shared__ int dests[TILE];
  const int tid = threadIdx.x;

  if (blockIdx.x < 128) {               // W transpose: 32768 elements over first 128 blocks
    int i = blockIdx.x * 256 + tid;
    int which = i >> 14, rem = i & 16383;
    int k = rem >> 7, nn = rem & 127;
    (which ? Wt2 : Wt1)[nn * 128 + k] = (_Float16)((which ? W2 : W1)[rem]);
  }

  int t0 = blockIdx.x * TILE;
  int cnt = min(E - t0, TILE);

  for (int i = tid; i < B; i += 256) h[i] = 0;
  __syncthreads();

  if (cnt == TILE) {
    int d[16], s_[16];
#pragma unroll
    for (int k = 0; k < 16; ++k) {
      d[k] = dst[t0 + tid + k * 256];
      s_[k] = src[t0 + tid + k * 256];
      atomicAdd(&h[d[k] >> BKT_SHIFT], 1);
    }
    __syncthreads();
    // wave-0: exclusive scan of h[0..B) -> lbase (7 bins per lane)
    if (tid < 64) {
      int l = tid, b7 = l * 7;
      int v[7]; int sum = 0;
#pragma unroll
      for (int q = 0; q < 7; ++q) { int b = b7 + q; v[q] = (b < B) ? h[b] : 0; sum += v[q]; }
      int incl = sum;
      for (int off = 1; off < 64; off <<= 1) { int y = __shfl_up(incl, off); if (l >= off) incl += y; }
      int run = incl - sum;
#pragma unroll
      for (int q = 0; q < 7; ++q) { int b = b7 + q; if (b < B) lbase[b] = run; run += v[q]; }
    }
    for (int i = tid; i < B; i += 256) {
      cur[i] = h[i] ? atomicAdd(&cursorPad[i * 16], h[i]) : 0;   // in-bucket reservation
      hcnt[i] = 0;
    }
    __syncthreads();
#pragma unroll
    for (int k = 0; k < 16; ++k) {
      int b = d[k] >> BKT_SHIFT;
      int r = atomicAdd(&hcnt[b], 1);
      int li = lbase[b] + r;
      int pos = cur[b] + r;
      staged[li] = (s_[k] << 8) | (d[k] & 255);
      dests[li] = (pos < CAP) ? (b * CAP + pos) : -1;
    }
    __syncthreads();
    for (int i = tid; i < TILE; i += 256) {
      int dd = dests[i];
      if (dd >= 0) pairs[dd] = staged[i];     // destination-sorted -> coalesced runs
    }
  } else {
    // tail block (one): simple path
    for (int e = tid; e < cnt; e += 256) atomicAdd(&h[dst[t0 + e] >> BKT_SHIFT], 1);
    __syncthreads();
    for (int i = tid; i < B; i += 256) {
      cur[i] = h[i] ? atomicAdd(&cursorPad[i * 16], h[i]) : 0;
      hcnt[i] = 0;
    }
    __syncthreads();
    for (int e = tid; e < cnt; e += 256) {
      int dd = dst[t0 + e];
      int b = dd >> BKT_SHIFT;
      int pos = cur[b] + atomicAdd(&hcnt[b], 1);
      if (pos < CAP) pairs[b * CAP + pos] = (src[t0 + e] << 8) | (dd & 255);
    }
  }
}

// ---------------- pass 2: per-bucket CSR, fully LDS-staged (coalesced pairs read + adj write) ----------------

__global__ __launch_bounds__(256) void k_csr(const int* __restrict__ pairs, const int* __restrict__ cursorPad,
                                             int* __restrict__ cnt, int* __restrict__ rowstart,
                                             float* __restrict__ dis, int* __restrict__ allocCtr,
                                             int* __restrict__ adj, int n) {
  __shared__ int pr[CAP];
  __shared__ int stagedAdj[PADMAX];
  __shared__ int deg[256];
  __shared__ int lcur[256];
  __shared__ int wsum[4];
  __shared__ int sbase;
  const int b = blockIdx.x, t = threadIdx.x;
  const int w = t >> 6, lane = t & 63;
  const int nodeBase = b << BKT_SHIFT;
  const int e0 = b * CAP;
  const int ecnt = min(cursorPad[b * 16], CAP);

  deg[t] = 0;
  for (int i = t; i < ecnt; i += 256) pr[i] = pairs[e0 + i];   // coalesced, read once
  __syncthreads();
  for (int i = t; i < ecnt; i += 256) atomicAdd(&deg[pr[i] & 255], 1);
  __syncthreads();

  int d = deg[t];
  int padded = (d + 3) & ~3;            // 16B-aligned adj rows for k_agg int4 loads
  // exclusive scan of padded over 256 threads: wave shfl-scan + wave offsets
  int incl = padded;
  for (int off = 1; off < 64; off <<= 1) { int y = __shfl_up(incl, off); if (lane >= off) incl += y; }
  if (lane == 63) wsum[w] = incl;
  __syncthreads();
  int tot  = wsum[0] + wsum[1] + wsum[2] + wsum[3];
  int woff = (w > 0 ? wsum[0] : 0) + (w > 1 ? wsum[1] : 0) + (w > 2 ? wsum[2] : 0);
  int excl = woff + incl - padded;
  if (t == 0) sbase = atomicAdd(allocCtr, tot);   // one bump per block
  lcur[t] = excl;
  __syncthreads();

  int base = sbase;
  int node = nodeBase + t;
  if (node < n) {
    rowstart[node] = base + excl;
    cnt[node] = d;
    dis[node] = rsqrtf((float)(d + 1));  // +1: self-loop included in reference degree
  }
  for (int i = t; i < ecnt; i += 256) {
    int pk = pr[i];
    int li = atomicAdd(&lcur[pk & 255], 1);
    stagedAdj[li] = pk >> 8;
  }
  __syncthreads();
  for (int i = t; i < tot; i += 256) adj[base + i] = stagedAdj[i];   // fully coalesced
}

// ---------------- MFMA GEMM: T = dis .* (A @ W), fp16 out (pre-scaled gather table) ----------------
// A32: A is fp32 (layer-1 input x, converted in-register); else fp16 (h1).

template <bool A32>
__global__ __launch_bounds__(256, 2) void k_gemm(const void* __restrict__ Av,
                                                 const _Float16* __restrict__ Wt,
                                                 const float* __restrict__ dis,
                                                 __half* __restrict__ T, int n, int nwaves) {
  const int wid = (blockIdx.x * 256 + threadIdx.x) >> 6;
  const int lane = threadIdx.x & 63;
  const int lrow = lane & 15;
  const int lk8 = (lane >> 4) * 8;
  const int ngroups = (n + 15) >> 4;

  half8 bf[8][4];
#pragma unroll
  for (int c = 0; c < 8; ++c)
#pragma unroll
    for (int kk = 0; kk < 4; ++kk)
      bf[c][kk] = *(const half8*)(Wt + (size_t)(c * 16 + lrow) * 128 + kk * 32 + lk8);

  for (int g = wid; g < ngroups; g += nwaves) {
    int ar = g * 16 + lrow; if (ar >= n) ar = n - 1;
    half8 af[4];
    if (A32) {
      const float* arow = (const float*)Av + (size_t)ar * 128 + lk8;
#pragma unroll
      for (int kk = 0; kk < 4; ++kk) {
        float4 v0 = *(const float4*)(arow + kk * 32);
        float4 v1 = *(const float4*)(arow + kk * 32 + 4);
        af[kk] = (half8){(_Float16)v0.x, (_Float16)v0.y, (_Float16)v0.z, (_Float16)v0.w,
                         (_Float16)v1.x, (_Float16)v1.y, (_Float16)v1.z, (_Float16)v1.w};
      }
    } else {
      const _Float16* arow = (const _Float16*)Av + (size_t)ar * 128 + lk8;
#pragma unroll
      for (int kk = 0; kk < 4; ++kk) af[kk] = *(const half8*)(arow + kk * 32);
    }
    f32x4 acc[8];
#pragma unroll
    for (int c = 0; c < 8; ++c) acc[c] = (f32x4){0.f, 0.f, 0.f, 0.f};
#pragma unroll
    for (int kk = 0; kk < 4; ++kk)
#pragma unroll
      for (int c = 0; c < 8; ++c)
        acc[c] = __builtin_amdgcn_mfma_f32_16x16x32_f16(af[kk], bf[c][kk], acc[c], 0, 0, 0);
    const int r0 = g * 16 + (lane >> 4) * 4;
#pragma unroll
    for (int r = 0; r < 4; ++r) {
      int row = r0 + r;
      if (row < n) {
        float sc = dis[row];
#pragma unroll
        for (int c = 0; c < 8; ++c)
          T[(size_t)row * 128 + c * 16 + lrow] = __float2half_rn(sc * acc[c][r]);
      }
    }
  }
}

// ---------------- aggregation + bias + relu: val[i] = relu(dis[i]*(t[i] + sum_j t[j]) + b) ----------------
// t pre-scaled by dis. FINAL: write fp32 out; else fp16 h (layer-2 GEMM input).

template <bool FINAL>
__global__ __launch_bounds__(256) void k_agg(const __half* __restrict__ t, const float* __restrict__ bias,
                                             const int* __restrict__ adj, const int* __restrict__ rowstart,
                                             const int* __restrict__ cnt, const float* __restrict__ dis,
                                             void* __restrict__ outV, int n) {
  int node = blockIdx.x * 4 + (threadIdx.x >> 6);
  if (node >= n) return;
  int lane = threadIdx.x & 63;
  int rs = rowstart[node];
  int d = cnt[node];
  float di = dis[node];
  float2 bb = ((const float2*)bias)[lane];
  float2 a = __half22float2(((const __half2*)(t + (size_t)node * FEAT))[lane]);
  float ax = a.x, ay = a.y;
  int p = rs, e = rs + d;
#pragma unroll 2
  for (; p + 4 <= e; p += 4) {
    int4 j4 = *(const int4*)(adj + p);   // aligned (rows 16B-aligned), wave-uniform
    float2 h0 = __half22float2(((const __half2*)(t + (size_t)j4.x * FEAT))[lane]);
    float2 h1 = __half22float2(((const __half2*)(t + (size_t)j4.y * FEAT))[lane]);
    float2 h2 = __half22float2(((const __half2*)(t + (size_t)j4.z * FEAT))[lane]);
    float2 h3 = __half22float2(((const __half2*)(t + (size_t)j4.w * FEAT))[lane]);
    ax += (h0.x + h1.x) + (h2.x + h3.x);
    ay += (h0.y + h1.y) + (h2.y + h3.y);
  }
  for (; p < e; ++p) {
    int j = adj[p];
    float2 hv = __half22float2(((const __half2*)(t + (size_t)j * FEAT))[lane]);
    ax += hv.x; ay += hv.y;
  }
  float vx = fmaxf(fmaf(di, ax, bb.x), 0.f);
  float vy = fmaxf(fmaf(di, ay, bb.y), 0.f);
  if (FINAL) ((float2*)((float*)outV + (size_t)node * FEAT))[lane] = make_float2(vx, vy);
  else       ((__half2*)((__half*)outV + (size_t)node * FEAT))[lane] = __floats2half2_rn(vx, vy);
}

// ---------------- launch ----------------

extern "C" void kernel_launch(void* const* d_in, const int* in_sizes, int n_in,
                              void* d_out, int out_size, void* d_ws, size_t ws_size,
                              hipStream_t stream) {
  const float* x  = (const float*)d_in[0];
  const int*   ei = (const int*)d_in[1];
  const float* W1 = (const float*)d_in[2];
  const float* b1 = (const float*)d_in[3];
  const float* W2 = (const float*)d_in[4];
  const float* b2 = (const float*)d_in[5];
  float* out = (float*)d_out;

  const int n = in_sizes[0] / FEAT;   // 100000
  const int E = in_sizes[1] / 2;      // 1600000
  const int B = (n + 255) >> BKT_SHIFT;   // 391 buckets (<= MAXB)
  const int* srcv = ei;
  const int* dstv = ei + E;

  uintptr_t p = (uintptr_t)d_ws;
  auto balloc = [&](size_t bytes) -> void* {
    void* r = (void*)p;
    p += (bytes + 255) & ~(size_t)255;
    return r;
  };
  __half*    T1   = (__half*)   balloc((size_t)n * FEAT * sizeof(__half)); // dis.*(x@W1)
  __half*    H1   = (__half*)   balloc((size_t)n * FEAT * sizeof(__half)); // h1 = relu(agg + b1)
  __half*    T2   = (__half*)   balloc((size_t)n * FEAT * sizeof(__half)); // dis.*(h1@W2)
  _Float16*  Wt1  = (_Float16*) balloc(128 * 128 * sizeof(_Float16));
  _Float16*  Wt2  = (_Float16*) balloc(128 * 128 * sizeof(_Float16));
  int*   cnt      = (int*)  balloc((size_t)n * sizeof(int));
  int*   rowstart = (int*)  balloc((size_t)n * sizeof(int));
  float* dis      = (float*)balloc((size_t)n * sizeof(float));
  int*   cursorPad= (int*)  balloc((size_t)MAXB * 16 * sizeof(int));       // 64B-padded bucket cursors
  int*   allocCtr = (int*)  balloc(256);                                   // adjacent to cursorPad
  int*   pairs    = (int*)  balloc((size_t)MAXB * CAP * sizeof(int));      // fixed bucket regions (packed)
  int*   adj      = (int*)  balloc(((size_t)E + 4 * (size_t)n) * sizeof(int)); // +pad for row alignment
  (void)ws_size; (void)n_in; (void)out_size;

  const int tb  = (E + TILE - 1) / TILE;          // 391 edge tiles
  const int ab  = (n + 3) / 4;                    // agg: 4 nodes (waves) per block
  const int gemmBlocks = 512;
  const int nwaves = gemmBlocks * 4;

  // zero bucket cursors + alloc counter (contiguous region), then build
  hipMemsetAsync(cursorPad, 0, (size_t)MAXB * 16 * sizeof(int) + 256, stream);
  k_bscatter<<<tb, 256, 0, stream>>>(srcv, dstv, cursorPad, pairs, E, B, W1, W2, Wt1, Wt2);
  k_csr     <<<B, 256, 0, stream>>>(pairs, cursorPad, cnt, rowstart, dis, allocCtr, adj, n);

  // layer 1: T1 = dis.*(x@W1)  ->  H1 = relu(di*agg(T1) + b1)
  k_gemm<true>  <<<gemmBlocks, 256, 0, stream>>>(x, Wt1, dis, T1, n, nwaves);
  k_agg<false>  <<<ab, 256, 0, stream>>>(T1, b1, adj, rowstart, cnt, dis, H1, n);

  // layer 2: T2 = dis.*(H1@W2) ->  out = relu(di*agg(T2) + b2)  (pooling is identity)
  k_gemm<false> <<<gemmBlocks, 256, 0, stream>>>(H1, Wt2, dis, T2, n, nwaves);
  k_agg<true>   <<<ab, 256, 0, stream>>>(T2, b2, adj, rowstart, cnt, dis, out, n);
}